// Round 2
// baseline (99.916 us; speedup 1.0000x reference)
//
#include <hip/hip_runtime.h>
#include <hip/hip_bf16.h>

#define N_SAMPLES 131072
#define N_EVENTS 128
#define N_ATOMS 32
#define ATOM_SIZE 512
#define LATENT 16
#define TIME_DIM 17
#define LAYERS 7

// dot of a 16-element f32 row with 16 floats in LDS
__device__ __forceinline__ float dot16f(const float* __restrict__ wr,
                                        const float* __restrict__ x) {
    const float4* q = (const float4*)wr;
    float4 a = q[0], b = q[1], c = q[2], d = q[3];
    float s = 0.f;
    s += a.x * x[0]  + a.y * x[1]  + a.z * x[2]  + a.w * x[3];
    s += b.x * x[4]  + b.y * x[5]  + b.z * x[6]  + b.w * x[7];
    s += c.x * x[8]  + c.y * x[9]  + c.z * x[10] + c.w * x[11];
    s += d.x * x[12] + d.y * x[13] + d.z * x[14] + d.w * x[15];
    return s;
}

// One block per event e (128 blocks x 64 threads).
// Walks the 7-layer binary tree path for event e (child bit c_i = (e>>(6-i))&1),
// accumulates time offsets, computes the hierarchical-dirac position
// p_e = sum_d [times[d][1] > times[d][0]] << (16-d), the atom coefficients,
// and the windowed+L2-normalized+amp-scaled 512-sample atom -> workspace.
__global__ __launch_bounds__(64) void expand_kernel(
    const float* __restrict__ base_latent,
    const float* __restrict__ to_time_W,
    const float* __restrict__ split_W,
    const float* __restrict__ split_b,
    const float* __restrict__ atoms,
    const float* __restrict__ to_atoms_W,
    const float* __restrict__ to_atoms_b,
    const float* __restrict__ to_amp_W,
    const float* __restrict__ to_amp_b,
    float* __restrict__ wsA,   // [128][512] scaled atom samples
    int* __restrict__ wsP)     // [128] positions
{
    const int e = blockIdx.x;
    const int t = threadIdx.x;

    __shared__ float x_cur[LATENT];
    __shared__ float x_next[LATENT];
    __shared__ float times[2 * TIME_DIM];
    __shared__ float a32[N_ATOMS];
    __shared__ float s_amp;

    if (t < LATENT) x_cur[t] = base_latent[t];
    if (t < 2 * TIME_DIM) times[t] = 0.f;
    __syncthreads();

    // --- tree walk ---
    for (int i = 0; i < LAYERS; ++i) {
        const int c = (e >> (6 - i)) & 1;
        if (t < LATENT) {
            // x_child[t] = split_W[i][c*16+t] . x + split_b[i][c*16+t]
            const int row = c * LATENT + t;
            x_next[t] = split_b[i * 32 + row] +
                        dot16f(split_W + (i * 32 + row) * LATENT, x_cur);
        } else if (t < LATENT + 2 * TIME_DIM) {
            // times[m] += to_time_W[i][c*34+m] . x   (m = 2*d + j)
            const int m = t - LATENT;
            const int row = c * (2 * TIME_DIM) + m;
            times[m] += dot16f(to_time_W + (i * 68 + row) * LATENT, x_cur);
        }
        __syncthreads();
        if (t < LATENT) x_cur[t] = x_next[t];
        __syncthreads();
    }

    // --- position p_e and amp ---
    if (t == 0) {
        int p = 0;
#pragma unroll
        for (int d = 0; d < TIME_DIM; ++d) {
            if (times[2 * d + 1] > times[2 * d]) p |= 1 << (16 - d);
        }
        wsP[e] = p;
        s_amp = to_amp_b[0] + dot16f(to_amp_W, x_cur);
    }
    // --- atom coefficients ---
    if (t < N_ATOMS) {
        a32[t] = to_atoms_b[t] + dot16f(to_atoms_W + t * LATENT, x_cur);
    }
    __syncthreads();

    // --- 512-sample atom: window * (a32 @ atoms), normalize, * amp ---
    float v[ATOM_SIZE / 64];
    float sumsq = 0.f;
#pragma unroll
    for (int it = 0; it < ATOM_SIZE / 64; ++it) {
        const int col = it * 64 + t;
        float acc = 0.f;
#pragma unroll
        for (int m = 0; m < N_ATOMS; ++m) {
            acc += a32[m] * atoms[m * ATOM_SIZE + col];
        }
        const float wnd =
            0.54f - 0.46f * cosf((float)col * (float)(M_PI / 256.0));
        const float val = wnd * acc;
        sumsq += val * val;
        v[it] = val;
    }
    // wave-64 butterfly reduce of sumsq
#pragma unroll
    for (int off = 32; off > 0; off >>= 1) sumsq += __shfl_xor(sumsq, off, 64);

    const float scale = s_amp / (sqrtf(sumsq) + 1e-8f);
#pragma unroll
    for (int it = 0; it < ATOM_SIZE / 64; ++it) {
        wsA[e * ATOM_SIZE + it * 64 + t] = v[it] * scale;
    }
}

// Gather: out[k] = sum_e wsA[e][k - p_e] for 0 <= k-p_e < 512.
// Per 256-sample block, prefilter the events whose segment overlaps.
__global__ __launch_bounds__(256) void gather_kernel(
    const float* __restrict__ wsA,
    const int* __restrict__ wsP,
    float* __restrict__ out)
{
    __shared__ int ev_p[N_EVENTS];
    __shared__ short ev_e[N_EVENTS];
    __shared__ int cnt;

    const int t = threadIdx.x;
    const int k0 = blockIdx.x * 256;

    if (t == 0) cnt = 0;
    __syncthreads();

    if (t < N_EVENTS) {
        const int p = wsP[t];
        // overlap iff p in [k0-511, k0+255]
        if (p + ATOM_SIZE > k0 && p < k0 + 256) {
            const int idx = atomicAdd(&cnt, 1);
            ev_p[idx] = p;
            ev_e[idx] = (short)t;
        }
    }
    __syncthreads();

    const int k = k0 + t;
    float sum = 0.f;
    const int n = cnt;
    for (int i = 0; i < n; ++i) {
        const unsigned d = (unsigned)(k - ev_p[i]);
        if (d < (unsigned)ATOM_SIZE) {
            sum += wsA[(int)ev_e[i] * ATOM_SIZE + (int)d];
        }
    }
    out[k] = sum;
}

extern "C" void kernel_launch(void* const* d_in, const int* in_sizes, int n_in,
                              void* d_out, int out_size, void* d_ws, size_t ws_size,
                              hipStream_t stream)
{
    const float* base_latent = (const float*)d_in[0];
    const float* to_time_W   = (const float*)d_in[1];
    const float* split_W     = (const float*)d_in[2];
    const float* split_b     = (const float*)d_in[3];
    const float* atoms       = (const float*)d_in[4];
    const float* to_atoms_W  = (const float*)d_in[5];
    const float* to_atoms_b  = (const float*)d_in[6];
    const float* to_amp_W    = (const float*)d_in[7];
    const float* to_amp_b    = (const float*)d_in[8];

    float* wsA = (float*)d_ws;                                   // 128*512 f32
    int*   wsP = (int*)((char*)d_ws + N_EVENTS * ATOM_SIZE * sizeof(float));

    expand_kernel<<<N_EVENTS, 64, 0, stream>>>(
        base_latent, to_time_W, split_W, split_b, atoms,
        to_atoms_W, to_atoms_b, to_amp_W, to_amp_b, wsA, wsP);

    gather_kernel<<<N_SAMPLES / 256, 256, 0, stream>>>(
        wsA, wsP, (float*)d_out);
}